// Round 2
// baseline (274.914 us; speedup 1.0000x reference)
//
#include <hip/hip_runtime.h>
#include <stdint.h>

// Problem constants
#define PP 196            // 14*14
#define BP 6272           // 32*196

// ---------------------------------------------------------------------------
// assign kernels: nearest-centroid 4-bit indices, packed 8 per u32.
// All distance math in f64 to match the numpy reference's argmin decisions
// exactly (f32 ordering differences flip near-ties and cascade).
// idx layout: idxp[cb/8][BP]
// ---------------------------------------------------------------------------

// 1x1 conv assign: dsub=4, codebook cb covers channels [4cb, 4cb+4)
// grid: (ceil(BP/256), ncb/8), block 256. in: [B][nchan][196]
template <typename T>
__global__ __launch_bounds__(256) void assign_1x1(
    const T* __restrict__ in, const float* __restrict__ cents,
    uint32_t* __restrict__ idxp, int nchan) {
  __shared__ double s_cent[8][16][4];
  __shared__ double s_c2[8][16];
  const int chunk = blockIdx.y;
  const int t = threadIdx.x;
  for (int i = t; i < 8 * 16 * 4; i += 256)
    ((double*)s_cent)[i] = (double)cents[(size_t)chunk * 512 + i];
  __syncthreads();
  if (t < 128) {
    int cb_l = t >> 4, k = t & 15;
    double s = 0.0;
#pragma unroll
    for (int d = 0; d < 4; d++) { double c = s_cent[cb_l][k][d]; s += c * c; }
    s_c2[cb_l][k] = s;
  }
  __syncthreads();
  const int p = blockIdx.x * 256 + t;
  if (p >= BP) return;
  const unsigned b = (unsigned)p / 196u;
  const unsigned pr = (unsigned)p - b * 196u;
  const T* xb = in + ((size_t)b * nchan + chunk * 32) * PP + pr;
  double xv[32];
#pragma unroll
  for (int i = 0; i < 32; i++) xv[i] = (double)xb[(size_t)i * PP];
  uint32_t word = 0;
#pragma unroll
  for (int cb_l = 0; cb_l < 8; cb_l++) {
    double best = 1e300; int bi = 0;
#pragma unroll
    for (int k = 0; k < 16; k++) {
      double dot = 0.0;
#pragma unroll
      for (int d = 0; d < 4; d++) dot = fma(xv[cb_l * 4 + d], s_cent[cb_l][k][d], dot);
      double dist = s_c2[cb_l][k] - 2.0 * dot;
      if (dist < best) { best = dist; bi = k; }   // strict < : first-min (jnp.argmin)
    }
    word |= (uint32_t)bi << (4 * cb_l);
  }
  idxp[(size_t)chunk * BP + p] = word;
}

// 3x3 conv assign: dsub=9 (one channel's 3x3 patch, row-major), pad=1.
// grid: (ceil(BP/256), 32), block 256. in: [B][256][196] (f64 activations)
__global__ __launch_bounds__(256) void assign_3x3(
    const double* __restrict__ in, const float* __restrict__ cents,
    uint32_t* __restrict__ idxp) {
  __shared__ double s_cent[8][16][9];
  __shared__ double s_c2[8][16];
  const int chunk = blockIdx.y;
  const int c0 = chunk * 8;
  const int t = threadIdx.x;
  for (int i = t; i < 8 * 16 * 9; i += 256)
    ((double*)s_cent)[i] = (double)cents[(size_t)c0 * 144 + i];
  __syncthreads();
  if (t < 128) {
    int cb_l = t >> 4, k = t & 15;
    double s = 0.0;
#pragma unroll
    for (int d = 0; d < 9; d++) { double c = s_cent[cb_l][k][d]; s += c * c; }
    s_c2[cb_l][k] = s;
  }
  __syncthreads();
  const int p = blockIdx.x * 256 + t;
  if (p >= BP) return;
  const unsigned b = (unsigned)p / 196u;
  const unsigned pr = (unsigned)p - b * 196u;
  const int oh = pr / 14, ow = pr - oh * 14;
  uint32_t word = 0;
  for (int cb_l = 0; cb_l < 8; cb_l++) {
    const double* base = in + ((size_t)b * 256 + (c0 + cb_l)) * PP;
    double v[9];
#pragma unroll
    for (int i = 0; i < 3; i++) {
#pragma unroll
      for (int j = 0; j < 3; j++) {
        int hh = oh + i - 1, ww = ow + j - 1;
        bool ok = (hh >= 0) & (hh < 14) & (ww >= 0) & (ww < 14);
        v[i * 3 + j] = ok ? base[hh * 14 + ww] : 0.0;
      }
    }
    double best = 1e300; int bi = 0;
#pragma unroll
    for (int k = 0; k < 16; k++) {
      double dot = 0.0;
#pragma unroll
      for (int d = 0; d < 9; d++) dot = fma(v[d], s_cent[cb_l][k][d], dot);
      double dist = s_c2[cb_l][k] - 2.0 * dot;
      if (dist < best) { best = dist; bi = k; }
    }
    word |= (uint32_t)bi << (4 * cb_l);
  }
  idxp[(size_t)chunk * BP + p] = word;
}

// ---------------------------------------------------------------------------
// accumulate: out[b][o][p] = act( scale[o]*sum_cb lut[cb][idx][o] + bias[o] (+res) )
// Accumulation in f64 (decision-grade precision for downstream argmin).
// grid: (49, NOUT/16), block 512 (8 waves): 128 positions x 16 out channels.
// LDS LUT chunk [16 cb][16 k][16 ch], k-stride padded to 36 floats ->
// 16B-aligned ds_read_b128 gathers, <=2 distinct addrs per bank group (free).
// ---------------------------------------------------------------------------
template <int NCB, int NOUT, bool RELU, bool RES, typename OutT>
__global__ __launch_bounds__(512) void accum_kernel(
    const float* __restrict__ lut, const uint32_t* __restrict__ idxp,
    const float* __restrict__ scale, const float* __restrict__ bias,
    const float* __restrict__ res, OutT* __restrict__ out) {
  __shared__ float s_lut[16 * 16 * 36];  // 36 KB
  const int t = threadIdx.x;
  const int lane = t & 63;
  const int wave = t >> 6;
  const int oquad = wave & 3;
  const int pg = wave >> 2;
  const int p = blockIdx.x * 128 + pg * 64 + lane;
  const int o_base = blockIdx.y * 16;
  const int r = t >> 1, h = t & 1;          // staging: row r=(cb,k), half h
  const int cb_ls = r >> 4, ks = r & 15;
  double a0 = 0.0, a1 = 0.0, a2 = 0.0, a3 = 0.0;
  constexpr int NCHUNK = NCB / 16;
  for (int ch = 0; ch < NCHUNK; ch++) {
    __syncthreads();  // prior chunk's gathers done before overwrite
    uint32_t w0 = idxp[(size_t)(ch * 2) * BP + p];
    uint32_t w1 = idxp[(size_t)(ch * 2 + 1) * BP + p];
    {
      const float* g = lut + (((size_t)(ch * 16 + cb_ls)) * 16 + ks) * NOUT + o_base + h * 8;
      float4 va = *(const float4*)g;
      float4 vb = *(const float4*)(g + 4);
      float* sd = s_lut + cb_ls * 576 + ks * 36 + h * 8;
      *(float4*)sd = va;
      *(float4*)(sd + 4) = vb;
    }
    __syncthreads();
#pragma unroll
    for (int cb_l = 0; cb_l < 16; cb_l++) {
      uint32_t w = (cb_l < 8) ? w0 : w1;
      int idx = (int)((w >> (4 * (cb_l & 7))) & 15u);
      const float4 v = *(const float4*)(s_lut + cb_l * 576 + idx * 36 + oquad * 4);
      a0 += (double)v.x; a1 += (double)v.y; a2 += (double)v.z; a3 += (double)v.w;
    }
  }
  const unsigned b = (unsigned)p / 196u;
  const unsigned pr = (unsigned)p - b * 196u;
  const int o = o_base + oquad * 4;
  const float4 sc = *(const float4*)(scale + o);
  const float4 bs = *(const float4*)(bias + o);
  double r0 = a0 * (double)sc.x + (double)bs.x;
  double r1 = a1 * (double)sc.y + (double)bs.y;
  double r2 = a2 * (double)sc.z + (double)bs.z;
  double r3 = a3 * (double)sc.w + (double)bs.w;
  if (RES) {
    const float* rp = res + ((size_t)b * NOUT + o) * PP + pr;
    r0 += (double)rp[0 * PP]; r1 += (double)rp[1 * PP];
    r2 += (double)rp[2 * PP]; r3 += (double)rp[3 * PP];
  }
  if (RELU) {
    r0 = fmax(r0, 0.0); r1 = fmax(r1, 0.0);
    r2 = fmax(r2, 0.0); r3 = fmax(r3, 0.0);
  }
  OutT* op = out + ((size_t)b * NOUT + o) * PP + pr;
  op[0 * PP] = (OutT)r0; op[1 * PP] = (OutT)r1;
  op[2 * PP] = (OutT)r2; op[3 * PP] = (OutT)r3;
}

// ---------------------------------------------------------------------------

extern "C" void kernel_launch(void* const* d_in, const int* in_sizes, int n_in,
                              void* d_out, int out_size, void* d_ws, size_t ws_size,
                              hipStream_t stream) {
  const float* x   = (const float*)d_in[0];   // [32,1024,14,14]
  const float* c1c = (const float*)d_in[1];   // [256,16,4]
  const float* c1l = (const float*)d_in[2];   // [256,16,256]
  const float* c1s = (const float*)d_in[3];
  const float* c1b = (const float*)d_in[4];
  const float* c2c = (const float*)d_in[5];   // [256,16,9]
  const float* c2l = (const float*)d_in[6];   // [256,16,256]
  const float* c2s = (const float*)d_in[7];
  const float* c2b = (const float*)d_in[8];
  const float* c3c = (const float*)d_in[9];   // [64,16,4]
  const float* c3l = (const float*)d_in[10];  // [64,16,1024]
  const float* c3s = (const float*)d_in[11];
  const float* c3b = (const float*)d_in[12];

  const size_t sz_i1 = (size_t)32 * BP * 4;        // 802,816 B
  const size_t sz_i2 = (size_t)32 * BP * 4;
  const size_t sz_i3 = (size_t)8 * BP * 4;         // 200,704 B
  const size_t sz_o64 = (size_t)BP * 256 * 8;      // 12.85 MB (f64 intermediate)

  char* w = (char*)d_ws;
  uint32_t* i1 = (uint32_t*)w; w += sz_i1;
  uint32_t* i2 = (uint32_t*)w; w += sz_i2;
  uint32_t* i3 = (uint32_t*)w; w += sz_i3;
  double *out1, *out2;
  if (ws_size >= sz_i1 + sz_i2 + sz_i3 + 2 * sz_o64) {
    out1 = (double*)w;
    out2 = (double*)(w + sz_o64);
  } else {
    // d_out is 32*1024*196 f32 = 25.69 MB = exactly 2 x 12.85 MB f64 arrays.
    // accum3 (final) reads only i3/x/lut3, then overwrites all of d_out.
    out1 = (double*)d_out;
    out2 = out1 + (size_t)BP * 256;
  }

  const dim3 blkA(256), blkC(512);
  // layer 1: 1x1, 256 codebooks (dsub=4) over 1024 input channels
  assign_1x1<float><<<dim3(25, 32), blkA, 0, stream>>>(x, c1c, i1, 1024);
  accum_kernel<256, 256, true, false, double><<<dim3(49, 16), blkC, 0, stream>>>(
      c1l, i1, c1s, c1b, nullptr, out1);
  // layer 2: 3x3, 256 codebooks (dsub=9)
  assign_3x3<<<dim3(25, 32), blkA, 0, stream>>>(out1, c2c, i2);
  accum_kernel<256, 256, true, false, double><<<dim3(49, 16), blkC, 0, stream>>>(
      c2l, i2, c2s, c2b, nullptr, out2);
  // layer 3: 1x1, 64 codebooks (dsub=4) over 256 channels; fused residual+relu
  assign_1x1<double><<<dim3(25, 8), blkA, 0, stream>>>(out2, c3c, i3, 256);
  accum_kernel<64, 1024, true, true, float><<<dim3(49, 64), blkC, 0, stream>>>(
      c3l, i3, c3s, c3b, x, (float*)d_out);
}